// Round 2
// baseline (1395.842 us; speedup 1.0000x reference)
//
#include <hip/hip_runtime.h>

// FPS with lazy chunk-UB pruning. B=64, N=262144, NPOINT=10.
// Round 1: full scan vs point 0 -> per-chunk (max,argmax) = fresh UBs.
// Rounds 2..9: min-dists only decrease, so stale chunk maxima are valid
// upper bounds. Cascade: scan highest-UB chunk, refresh, stop when
// maxUB < best (strict: UB==best could hide a lower-index tie).
// Scans recompute dmin from the full center list in reference order -> exact.

#define NPOINT 10
#define NB     64
#define NPTS   262144
#define G      64
#define CH     (NPTS / G)              // 4096 pts per chunk
#define TPB_A  256
#define PPT_A  4
#define NPASS_A (CH / (TPB_A * PPT_A)) // 4
#define TPB_B  1024
#define PPT_B  (CH / TPB_B)            // 4
#define INIT_DIST 1e10f

// Strict IEEE, reference association order, no FMA contraction.
__device__ __forceinline__ float sqdist(float x, float y, float z,
                                        float cx, float cy, float cz) {
    float dx = x - cx, dy = y - cy, dz = z - cz;
    return __fadd_rn(__fadd_rn(__fmul_rn(dx, dx), __fmul_rn(dy, dy)),
                     __fmul_rn(dz, dz));
}

// Kernel A: dmin vs center 0 (= xyz[b,0]), per-chunk max + first-argmax.
__global__ __launch_bounds__(TPB_A) void fps_scan1(
    const float* __restrict__ xyz,
    float* __restrict__ ub, int* __restrict__ uidx)
{
    const int b = blockIdx.y, g = blockIdx.x, tid = threadIdx.x;
    const float* xyzb = xyz + (size_t)b * NPTS * 3;
    const float cx = xyzb[0], cy = xyzb[1], cz = xyzb[2];

    __shared__ float s_v[TPB_A];
    __shared__ int   s_i[TPB_A];

    float bestv = -1.0f; int besti = 0;
    const int base = g * CH;
    #pragma unroll
    for (int pass = 0; pass < NPASS_A; ++pass) {
        const int p0 = base + pass * (TPB_A * PPT_A) + tid * PPT_A;
        const float4* src = (const float4*)(xyzb + (size_t)p0 * 3);
        float4 a = src[0], c4 = src[1], e = src[2];
        float px[4] = {a.x, a.w, c4.z, e.y};
        float py[4] = {a.y, c4.x, c4.w, e.z};
        float pz[4] = {a.z, c4.y, e.x, e.w};
        #pragma unroll
        for (int j = 0; j < 4; ++j) {
            float d = fminf(INIT_DIST, sqdist(px[j], py[j], pz[j], cx, cy, cz));
            if (d > bestv) { bestv = d; besti = p0 + j; }  // ascending j: first wins
        }
    }
    s_v[tid] = bestv; s_i[tid] = besti;
    __syncthreads();
    for (int st = TPB_A / 2; st > 0; st >>= 1) {
        if (tid < st) {
            float ov = s_v[tid + st]; int oi = s_i[tid + st];
            if (ov > s_v[tid] || (ov == s_v[tid] && oi < s_i[tid])) {
                s_v[tid] = ov; s_i[tid] = oi;
            }
        }
        __syncthreads();
    }
    if (tid == 0) { ub[b * G + g] = s_v[0]; uidx[b * G + g] = s_i[0]; }
}

// Kernel B: one block per batch. Round-1 argmax from fresh partials, then
// cascaded pruned scans for rounds 2..9.
__global__ __launch_bounds__(TPB_B) void fps_rounds(
    const float* __restrict__ xyz, int* __restrict__ out,
    const float* __restrict__ ub_in, const int* __restrict__ uidx_in)
{
    const int b = blockIdx.x, tid = threadIdx.x;
    const int lane = tid & 63, wave = tid >> 6;    // 16 waves
    const float* xyzb = xyz + (size_t)b * NPTS * 3;

    __shared__ float s_ub[G];
    __shared__ float s_cx[NPOINT], s_cy[NPOINT], s_cz[NPOINT];
    __shared__ float s_rv[16]; __shared__ int s_ri[16];
    __shared__ float s_bestv; __shared__ int s_besti;
    __shared__ int   s_ctl;
    __shared__ unsigned s_sc0, s_sc1;

    if (tid < G) s_ub[tid] = ub_in[b * G + tid];

    // ---- round 1: reduce fresh per-chunk partials (centers = {pt0}) ----
    if (tid < 64) {
        float v = ub_in[b * G + tid];
        int   i = uidx_in[b * G + tid];
        #pragma unroll
        for (int off = 32; off > 0; off >>= 1) {
            float ov = __shfl_down(v, off); int oi = __shfl_down(i, off);
            if (ov > v || (ov == v && oi < i)) { v = ov; i = oi; }
        }
        if (tid == 0) {
            out[b * NPOINT + 0] = 0;
            out[b * NPOINT + 1] = i;
            s_cx[0] = xyzb[0]; s_cy[0] = xyzb[1]; s_cz[0] = xyzb[2];
            size_t o = (size_t)i * 3;
            s_cx[1] = xyzb[o]; s_cy[1] = xyzb[o + 1]; s_cz[1] = xyzb[o + 2];
        }
    }
    __syncthreads();

    // ---- rounds 2..9: pruned cascade ----
    for (int r = 2; r < NPOINT; ++r) {
        if (tid == 0) { s_bestv = -1.0f; s_besti = 0; s_sc0 = 0u; s_sc1 = 0u; }
        __syncthreads();
        while (true) {
            // pick unscanned chunk with max (stale) UB; -1 if pruned out
            if (tid < 64) {
                unsigned m = (tid < 32) ? s_sc0 : s_sc1;
                bool sc = (m >> (tid & 31)) & 1u;
                float v = sc ? -1.0f : s_ub[tid];
                int   c = tid;
                #pragma unroll
                for (int off = 32; off > 0; off >>= 1) {
                    float ov = __shfl_down(v, off); int oc = __shfl_down(c, off);
                    if (ov > v) { v = ov; c = oc; }
                }
                if (tid == 0) {
                    if (v < s_bestv) s_ctl = -1;   // strict: keep ties scannable
                    else {
                        s_ctl = c;
                        if (c < 32) s_sc0 |= 1u << c; else s_sc1 |= 1u << (c - 32);
                    }
                }
            }
            __syncthreads();
            const int c = s_ctl;
            if (c < 0) break;

            // exact rescan of chunk c over centers 0..r-1 (reference order)
            float cx[NPOINT], cy[NPOINT], cz[NPOINT];
            #pragma unroll
            for (int k = 0; k < NPOINT; ++k) { cx[k] = s_cx[k]; cy[k] = s_cy[k]; cz[k] = s_cz[k]; }
            const int p0 = c * CH + tid * PPT_B;
            const float4* src = (const float4*)(xyzb + (size_t)p0 * 3);
            float4 a = src[0], c4 = src[1], e = src[2];
            float px[4] = {a.x, a.w, c4.z, e.y};
            float py[4] = {a.y, c4.x, c4.w, e.z};
            float pz[4] = {a.z, c4.y, e.x, e.w};
            float lv = -1.0f; int li = 0;
            #pragma unroll
            for (int j = 0; j < 4; ++j) {
                float dmin = INIT_DIST;
                #pragma unroll
                for (int k = 0; k < NPOINT; ++k) {
                    float d = sqdist(px[j], py[j], pz[j], cx[k], cy[k], cz[k]);
                    dmin = (k < r) ? fminf(dmin, d) : dmin;   // order-preserving
                }
                if (dmin > lv) { lv = dmin; li = p0 + j; }
            }
            #pragma unroll
            for (int off = 32; off > 0; off >>= 1) {
                float ov = __shfl_down(lv, off); int oi = __shfl_down(li, off);
                if (ov > lv || (ov == lv && oi < li)) { lv = ov; li = oi; }
            }
            if (lane == 0) { s_rv[wave] = lv; s_ri[wave] = li; }
            __syncthreads();
            if (tid < 64) {
                float v2 = (tid < 16) ? s_rv[tid] : -1.0f;
                int   i2 = (tid < 16) ? s_ri[tid] : 0x7fffffff;
                #pragma unroll
                for (int off = 8; off > 0; off >>= 1) {
                    float ov = __shfl_down(v2, off); int oi = __shfl_down(i2, off);
                    if (ov > v2 || (ov == v2 && oi < i2)) { v2 = ov; i2 = oi; }
                }
                if (tid == 0) {
                    s_ub[c] = v2;                    // refreshed exact max
                    if (v2 > s_bestv || (v2 == s_bestv && i2 < s_besti)) {
                        s_bestv = v2; s_besti = i2;
                    }
                }
            }
            __syncthreads();
        }
        if (tid == 0) {
            out[b * NPOINT + r] = s_besti;
            size_t o = (size_t)s_besti * 3;
            s_cx[r] = xyzb[o]; s_cy[r] = xyzb[o + 1]; s_cz[r] = xyzb[o + 2];
        }
        __syncthreads();
    }
}

extern "C" void kernel_launch(void* const* d_in, const int* in_sizes, int n_in,
                              void* d_out, int out_size, void* d_ws, size_t ws_size,
                              hipStream_t stream) {
    const float* xyz = (const float*)d_in[0];
    int* out = (int*)d_out;
    char* ws = (char*)d_ws;
    float* ub   = (float*)ws;                    // 64*64*4 = 16 KB
    int*   uidx = (int*)(ws + (size_t)G * NB * 4);

    fps_scan1<<<dim3(G, NB), dim3(TPB_A), 0, stream>>>(xyz, ub, uidx);
    fps_rounds<<<dim3(NB), dim3(TPB_B), 0, stream>>>(xyz, out, ub, uidx);
}

// Round 4
// 390.478 us; speedup vs baseline: 3.5747x; 3.5747x over previous
//
#include <hip/hip_runtime.h>

// FPS, breadth-parallel lazy chunk-UB pruning. B=64, N=262144, NPOINT=10.
// scan1: full exact pass vs point 0 -> per-chunk (max,idx) = fresh UBs.
// step r (2..9): seed kernel scans the top-stale-UB chunk -> LB; rest kernel
// prunes chunks with staleUB < LB and rescans survivors IN PARALLEL,
// merging results via packed u64 atomicMax (exact val, lowest-index ties).
// R3 bugfix: fps_seed must load centers 0..R-2 from ws_sel (was 0..R-3,
// leaving scx[R-2] uninitialized garbage from step 3 on).

#define NPOINT 10
#define NB     64
#define NPTS   262144
#define G      64
#define CH     (NPTS / G)        // 4096
#define TPB    256
#define PPT    (CH / TPB)        // 16 pts/thread in chunk scans
#define INIT_DIST 1e10f

// Strict IEEE, reference association order ((dx^2+dy^2)+dz^2), no contraction.
__device__ __forceinline__ float sqdist(float x, float y, float z,
                                        float cx, float cy, float cz) {
    float dx = x - cx, dy = y - cy, dz = z - cz;
    return __fadd_rn(__fadd_rn(__fmul_rn(dx, dx), __fmul_rn(dy, dy)),
                     __fmul_rn(dz, dz));
}

// Pack (value, index) so u64 max == (max value, ties -> lowest index).
// Values are squared distances >= 0, so float bits are monotone.
__device__ __forceinline__ unsigned long long packvi(float v, int i) {
    return ((unsigned long long)__float_as_uint(v) << 32) |
           (unsigned)(0xFFFFFFFFu - (unsigned)i);
}
__device__ __forceinline__ int unpack_idx(unsigned long long w) {
    return (int)(0xFFFFFFFFu - (unsigned)(w & 0xFFFFFFFFull));
}

// Exact scan of chunk c against centers 0..R-1 (in LDS) -> thread-local best.
template <int R>
__device__ __forceinline__ void scan_chunk(const float* __restrict__ xyzb,
                                           int c, int tid,
                                           const float* scx, const float* scy,
                                           const float* scz,
                                           float& outv, int& outi) {
    float cx[R], cy[R], cz[R];
    #pragma unroll
    for (int k = 0; k < R; ++k) { cx[k] = scx[k]; cy[k] = scy[k]; cz[k] = scz[k]; }

    float bestv = -1.0f; int besti = 0;
    const int p0 = c * CH + tid * PPT;
    #pragma unroll
    for (int grp = 0; grp < PPT / 4; ++grp) {
        const float4* src = (const float4*)(xyzb + (size_t)(p0 + grp * 4) * 3);
        float4 a = src[0], c4 = src[1], e = src[2];
        float px[4] = {a.x, a.w, c4.z, e.y};
        float py[4] = {a.y, c4.x, c4.w, e.z};
        float pz[4] = {a.z, c4.y, e.x, e.w};
        #pragma unroll
        for (int j = 0; j < 4; ++j) {
            float dmin = INIT_DIST;
            #pragma unroll
            for (int k = 0; k < R; ++k)
                dmin = fminf(dmin, sqdist(px[j], py[j], pz[j], cx[k], cy[k], cz[k]));
            if (dmin > bestv) { bestv = dmin; besti = p0 + grp * 4 + j; }
        }
    }
    outv = bestv; outi = besti;
}

// LDS block argmax reduce (max value, ties -> lowest index).
__device__ __forceinline__ void block_reduce(float& v, int& i, int tid,
                                             float* s_v, int* s_i) {
    s_v[tid] = v; s_i[tid] = i;
    __syncthreads();
    for (int st = TPB / 2; st > 0; st >>= 1) {
        if (tid < st) {
            float ov = s_v[tid + st]; int oi = s_i[tid + st];
            if (ov > s_v[tid] || (ov == s_v[tid] && oi < s_i[tid])) {
                s_v[tid] = ov; s_i[tid] = oi;
            }
        }
        __syncthreads();
    }
    v = s_v[0]; i = s_i[0];
}

// ---- Kernel A: full exact scan vs center 0 -> per-chunk (max, first-argmax)
__global__ __launch_bounds__(TPB) void fps_scan1(
    const float* __restrict__ xyz,
    float* __restrict__ ub, int* __restrict__ uidx)
{
    const int b = blockIdx.y, g = blockIdx.x, tid = threadIdx.x;
    const float* xyzb = xyz + (size_t)b * NPTS * 3;
    const float cx = xyzb[0], cy = xyzb[1], cz = xyzb[2];
    __shared__ float s_v[TPB];
    __shared__ int   s_i[TPB];

    float bestv = -1.0f; int besti = 0;
    // 4096 pts, 256 thr -> 16 pts/thread = 4 groups of 4 points
    const int p0 = g * CH + tid * PPT;
    #pragma unroll
    for (int grp = 0; grp < PPT / 4; ++grp) {
        const float4* src = (const float4*)(xyzb + (size_t)(p0 + grp * 4) * 3);
        float4 a = src[0], c4 = src[1], e = src[2];
        float px[4] = {a.x, a.w, c4.z, e.y};
        float py[4] = {a.y, c4.x, c4.w, e.z};
        float pz[4] = {a.z, c4.y, e.x, e.w};
        #pragma unroll
        for (int j = 0; j < 4; ++j) {
            float d = fminf(INIT_DIST, sqdist(px[j], py[j], pz[j], cx, cy, cz));
            if (d > bestv) { bestv = d; besti = p0 + grp * 4 + j; }
        }
    }
    block_reduce(bestv, besti, tid, s_v, s_i);
    if (tid == 0) { ub[b * G + g] = bestv; uidx[b * G + g] = besti; }
}

// ---- Kernel B: per-step seed. Resolve step R-1 winner, pick top-UB chunk
// (excluding the just-resolved winner's chunk), scan it -> LB.
template <int R>
__global__ __launch_bounds__(TPB) void fps_seed(
    const float* __restrict__ xyz, int* __restrict__ out,
    float4* __restrict__ ws_sel,
    float* __restrict__ ub, const int* __restrict__ uidx,
    unsigned long long* __restrict__ winner,
    float* __restrict__ lb, int* __restrict__ seedc)
{
    const int b = blockIdx.x, tid = threadIdx.x;
    const float* xyzb = xyz + (size_t)b * NPTS * 3;
    __shared__ float scx[NPOINT], scy[NPOINT], scz[NPOINT];
    __shared__ int   s_prev, s_seed;
    __shared__ float s_v[TPB];
    __shared__ int   s_i[TPB];

    // centers 0..R-2 persisted by earlier seed kernels (R3 fix: R-1, not R-2)
    if constexpr (R > 2) {
        if (tid < R - 1) {
            float4 q = ws_sel[b * NPOINT + tid];
            scx[tid] = q.x; scy[tid] = q.y; scz[tid] = q.z;
        }
    }

    // resolve winner of step R-1 -> center R-1
    if constexpr (R == 2) {
        if (tid == 0) {
            scx[0] = xyzb[0]; scy[0] = xyzb[1]; scz[0] = xyzb[2];
            out[b * NPOINT + 0] = 0;
            ws_sel[b * NPOINT + 0] = make_float4(scx[0], scy[0], scz[0], 0.f);
        }
        if (tid < 64) {
            float v = ub[b * G + tid]; int i = uidx[b * G + tid];
            #pragma unroll
            for (int off = 32; off > 0; off >>= 1) {
                float ov = __shfl_down(v, off); int oi = __shfl_down(i, off);
                if (ov > v || (ov == v && oi < i)) { v = ov; i = oi; }
            }
            if (tid == 0) s_prev = i;
        }
    } else {
        if (tid == 0) s_prev = unpack_idx(winner[b]);
    }
    __syncthreads();
    const int prevIdx = s_prev;
    if (tid == 0) {
        size_t o = (size_t)prevIdx * 3;
        float nx = xyzb[o], ny = xyzb[o + 1], nz = xyzb[o + 2];
        scx[R - 1] = nx; scy[R - 1] = ny; scz[R - 1] = nz;
        out[b * NPOINT + (R - 1)] = prevIdx;
        ws_sel[b * NPOINT + (R - 1)] = make_float4(nx, ny, nz, 0.f);
    }

    // pick seed chunk: argmax stale UB, excluding prev winner's chunk
    if (tid < 64) {
        const int pc = prevIdx / CH;
        float v = (tid == pc) ? -1.0f : ub[b * G + tid];
        int c = tid;
        #pragma unroll
        for (int off = 32; off > 0; off >>= 1) {
            float ov = __shfl_down(v, off); int oc = __shfl_down(c, off);
            if (ov > v || (ov == v && oc < c)) { v = ov; c = oc; }
        }
        if (tid == 0) { s_seed = c; seedc[b] = c; }
    }
    __syncthreads();

    float v; int i;
    scan_chunk<R>(xyzb, s_seed, tid, scx, scy, scz, v, i);
    block_reduce(v, i, tid, s_v, s_i);
    if (tid == 0) {
        ub[b * G + s_seed] = v;
        lb[b] = v;
        winner[b] = packvi(v, i);
    }
}

// ---- Kernel C: per-step survivors. Prune by stale UB vs LB; rescan rest.
template <int R>
__global__ __launch_bounds__(TPB) void fps_rest(
    const float* __restrict__ xyz, const float4* __restrict__ ws_sel,
    float* __restrict__ ub, unsigned long long* __restrict__ winner,
    const float* __restrict__ lb, const int* __restrict__ seedc)
{
    const int c = blockIdx.x, b = blockIdx.y, tid = threadIdx.x;
    if (c == seedc[b]) return;                 // already scanned by seed
    if (ub[b * G + c] < lb[b]) return;         // strict: ties stay scannable

    const float* xyzb = xyz + (size_t)b * NPTS * 3;
    __shared__ float scx[NPOINT], scy[NPOINT], scz[NPOINT];
    __shared__ float s_v[TPB];
    __shared__ int   s_i[TPB];
    if (tid < R) {
        float4 q = ws_sel[b * NPOINT + tid];
        scx[tid] = q.x; scy[tid] = q.y; scz[tid] = q.z;
    }
    __syncthreads();

    float v; int i;
    scan_chunk<R>(xyzb, c, tid, scx, scy, scz, v, i);
    block_reduce(v, i, tid, s_v, s_i);
    if (tid == 0) {
        ub[b * G + c] = v;                     // refresh exact chunk max
        atomicMax(&winner[b], packvi(v, i));
    }
}

// ---- Final: decode step-9 winners.
__global__ __launch_bounds__(64) void fps_final(
    const unsigned long long* __restrict__ winner, int* __restrict__ out)
{
    const int b = threadIdx.x;
    if (b < NB) out[b * NPOINT + (NPOINT - 1)] = unpack_idx(winner[b]);
}

extern "C" void kernel_launch(void* const* d_in, const int* in_sizes, int n_in,
                              void* d_out, int out_size, void* d_ws, size_t ws_size,
                              hipStream_t stream) {
    const float* xyz = (const float*)d_in[0];
    int* out = (int*)d_out;
    char* ws = (char*)d_ws;

    float*  ub     = (float*)ws;                         // 16 KB
    int*    uidx   = (int*)(ws + 16384);                 // 16 KB
    float4* ws_sel = (float4*)(ws + 32768);              // 10 KB
    unsigned long long* winner = (unsigned long long*)(ws + 43008); // 512 B
    float*  lb     = (float*)(ws + 43520);               // 256 B
    int*    seedc  = (int*)(ws + 43776);                 // 256 B

    fps_scan1<<<dim3(G, NB), dim3(TPB), 0, stream>>>(xyz, ub, uidx);

    fps_seed<2><<<dim3(NB), dim3(TPB), 0, stream>>>(xyz, out, ws_sel, ub, uidx, winner, lb, seedc);
    fps_rest<2><<<dim3(G, NB), dim3(TPB), 0, stream>>>(xyz, ws_sel, ub, winner, lb, seedc);
    fps_seed<3><<<dim3(NB), dim3(TPB), 0, stream>>>(xyz, out, ws_sel, ub, uidx, winner, lb, seedc);
    fps_rest<3><<<dim3(G, NB), dim3(TPB), 0, stream>>>(xyz, ws_sel, ub, winner, lb, seedc);
    fps_seed<4><<<dim3(NB), dim3(TPB), 0, stream>>>(xyz, out, ws_sel, ub, uidx, winner, lb, seedc);
    fps_rest<4><<<dim3(G, NB), dim3(TPB), 0, stream>>>(xyz, ws_sel, ub, winner, lb, seedc);
    fps_seed<5><<<dim3(NB), dim3(TPB), 0, stream>>>(xyz, out, ws_sel, ub, uidx, winner, lb, seedc);
    fps_rest<5><<<dim3(G, NB), dim3(TPB), 0, stream>>>(xyz, ws_sel, ub, winner, lb, seedc);
    fps_seed<6><<<dim3(NB), dim3(TPB), 0, stream>>>(xyz, out, ws_sel, ub, uidx, winner, lb, seedc);
    fps_rest<6><<<dim3(G, NB), dim3(TPB), 0, stream>>>(xyz, ws_sel, ub, winner, lb, seedc);
    fps_seed<7><<<dim3(NB), dim3(TPB), 0, stream>>>(xyz, out, ws_sel, ub, uidx, winner, lb, seedc);
    fps_rest<7><<<dim3(G, NB), dim3(TPB), 0, stream>>>(xyz, ws_sel, ub, winner, lb, seedc);
    fps_seed<8><<<dim3(NB), dim3(TPB), 0, stream>>>(xyz, out, ws_sel, ub, uidx, winner, lb, seedc);
    fps_rest<8><<<dim3(G, NB), dim3(TPB), 0, stream>>>(xyz, ws_sel, ub, winner, lb, seedc);
    fps_seed<9><<<dim3(NB), dim3(TPB), 0, stream>>>(xyz, out, ws_sel, ub, uidx, winner, lb, seedc);
    fps_rest<9><<<dim3(G, NB), dim3(TPB), 0, stream>>>(xyz, ws_sel, ub, winner, lb, seedc);

    fps_final<<<dim3(1), dim3(64), 0, stream>>>(winner, out);
}

// Round 5
// 223.422 us; speedup vs baseline: 6.2476x; 1.7477x over previous
//
#include <hip/hip_runtime.h>

// FPS, one self-contained kernel per step. B=64, N=262144, NPOINT=10.
// Per-chunk state (double-buffered by step parity):
//   ub[c]   = stale upper bound (chunk max at last rescan; monotone-valid)
//   uidx[c] = argmax point index at last rescan
//   cand[c] = EXACT current min-dist of point uidx[c] (refreshed 1 dist/step)
// Step R: every block redundantly computes LB = max_c cand'[c] (cand
// refreshed vs the newly resolved center), prunes its chunk if ub < LB
// (strict: ties stay scannable), else rescans exactly and atomicMaxes a
// packed (val, ~idx) winner -> max value, lowest index, order-independent.

#define NPOINT 10
#define NB     64
#define NPTS   262144
#define G      64
#define CH     (NPTS / G)        // 4096
#define TPB    256
#define PPT    (CH / TPB)        // 16
#define INIT_DIST 1e10f

// Strict IEEE, reference association order ((dx^2+dy^2)+dz^2), no contraction.
__device__ __forceinline__ float sqdist(float x, float y, float z,
                                        float cx, float cy, float cz) {
    float dx = x - cx, dy = y - cy, dz = z - cz;
    return __fadd_rn(__fadd_rn(__fmul_rn(dx, dx), __fmul_rn(dy, dy)),
                     __fmul_rn(dz, dz));
}

__device__ __forceinline__ unsigned long long packvi(float v, int i) {
    return ((unsigned long long)__float_as_uint(v) << 32) |
           (unsigned)(0xFFFFFFFFu - (unsigned)i);
}
__device__ __forceinline__ int unpack_idx(unsigned long long w) {
    return (int)(0xFFFFFFFFu - (unsigned)(w & 0xFFFFFFFFull));
}

// 64-lane shfl argmax (max val, ties -> lowest idx); result in lane 0.
__device__ __forceinline__ void wave_argmax(float& v, int& i) {
    #pragma unroll
    for (int off = 32; off > 0; off >>= 1) {
        float ov = __shfl_down(v, off); int oi = __shfl_down(i, off);
        if (ov > v || (ov == v && oi < i)) { v = ov; i = oi; }
    }
}

template <int R>
__device__ __forceinline__ void scan_chunk(const float* __restrict__ xyzb,
                                           int c, int tid,
                                           const float* scx, const float* scy,
                                           const float* scz,
                                           float& outv, int& outi) {
    float cx[R], cy[R], cz[R];
    #pragma unroll
    for (int k = 0; k < R; ++k) { cx[k] = scx[k]; cy[k] = scy[k]; cz[k] = scz[k]; }
    float bestv = -1.0f; int besti = 0;
    const int p0 = c * CH + tid * PPT;
    #pragma unroll
    for (int grp = 0; grp < PPT / 4; ++grp) {
        const float4* src = (const float4*)(xyzb + (size_t)(p0 + grp * 4) * 3);
        float4 a = src[0], c4 = src[1], e = src[2];
        float px[4] = {a.x, a.w, c4.z, e.y};
        float py[4] = {a.y, c4.x, c4.w, e.z};
        float pz[4] = {a.z, c4.y, e.x, e.w};
        #pragma unroll
        for (int j = 0; j < 4; ++j) {
            float dmin = INIT_DIST;
            #pragma unroll
            for (int k = 0; k < R; ++k)
                dmin = fminf(dmin, sqdist(px[j], py[j], pz[j], cx[k], cy[k], cz[k]));
            if (dmin > bestv) { bestv = dmin; besti = p0 + grp * 4 + j; }
        }
    }
    outv = bestv; outi = besti;
}

// ---- Kernel A: full scan vs center 0 -> fresh (ub, uidx, cand=ub).
__global__ __launch_bounds__(TPB) void fps_scan1(
    const float* __restrict__ xyz,
    float* __restrict__ ub, int* __restrict__ uidx, float* __restrict__ cand)
{
    const int b = blockIdx.y, g = blockIdx.x, tid = threadIdx.x;
    const int lane = tid & 63, wave = tid >> 6;
    const float* xyzb = xyz + (size_t)b * NPTS * 3;
    const float cx = xyzb[0], cy = xyzb[1], cz = xyzb[2];
    __shared__ float s_v[4];
    __shared__ int   s_i[4];

    float bestv = -1.0f; int besti = 0;
    const int p0 = g * CH + tid * PPT;
    #pragma unroll
    for (int grp = 0; grp < PPT / 4; ++grp) {
        const float4* src = (const float4*)(xyzb + (size_t)(p0 + grp * 4) * 3);
        float4 a = src[0], c4 = src[1], e = src[2];
        float px[4] = {a.x, a.w, c4.z, e.y};
        float py[4] = {a.y, c4.x, c4.w, e.z};
        float pz[4] = {a.z, c4.y, e.x, e.w};
        #pragma unroll
        for (int j = 0; j < 4; ++j) {
            float d = fminf(INIT_DIST, sqdist(px[j], py[j], pz[j], cx, cy, cz));
            if (d > bestv) { bestv = d; besti = p0 + grp * 4 + j; }
        }
    }
    wave_argmax(bestv, besti);
    if (lane == 0) { s_v[wave] = bestv; s_i[wave] = besti; }
    __syncthreads();
    if (tid == 0) {
        float v = s_v[0]; int i = s_i[0];
        #pragma unroll
        for (int w = 1; w < 4; ++w) {
            float ov = s_v[w]; int oi = s_i[w];
            if (ov > v || (ov == v && oi < i)) { v = ov; i = oi; }
        }
        ub[b * G + g] = v; uidx[b * G + g] = i; cand[b * G + g] = v;
    }
}

// ---- Kernel B: one self-contained FPS step.
template <int R>
__global__ __launch_bounds__(TPB) void fps_step(
    const float* __restrict__ xyz, int* __restrict__ out,
    float4* __restrict__ ws_sel,
    const float* __restrict__ ub_in,  float* __restrict__ ub_out,
    const int*   __restrict__ uidx_in, int* __restrict__ uidx_out,
    const float* __restrict__ cand_in, float* __restrict__ cand_out,
    const unsigned long long* __restrict__ win_in,
    unsigned long long* __restrict__ win_out)
{
    const int c = blockIdx.x, b = blockIdx.y, tid = threadIdx.x;
    const int lane = tid & 63, wave = tid >> 6;
    const float* xyzb = xyz + (size_t)b * NPTS * 3;

    __shared__ float s_v[4];
    __shared__ int   s_i[4];
    __shared__ int   s_prev;
    __shared__ float s_lb, s_cdown;
    __shared__ float scx[NPOINT], scy[NPOINT], scz[NPOINT];

    // 1. resolve winner of step R-1 -> center R-1
    int prevIdx;
    if constexpr (R == 2) {
        if (tid < 64) {
            float v = ub_in[b * G + tid]; int i = uidx_in[b * G + tid];
            wave_argmax(v, i);
            if (tid == 0) s_prev = i;
        }
        __syncthreads();
        prevIdx = s_prev;
    } else {
        prevIdx = unpack_idx(win_in[b]);       // uniform load
    }
    const size_t po = (size_t)prevIdx * 3;
    const float pcx = xyzb[po], pcy = xyzb[po + 1], pcz = xyzb[po + 2];

    // 2. refresh cands vs new center; LB = max_c cand'[c] (exact point vals)
    if (tid < 64) {
        int pi = uidx_in[b * G + tid];
        size_t qo = (size_t)pi * 3;
        float cd = fminf(cand_in[b * G + tid],
                         sqdist(xyzb[qo], xyzb[qo + 1], xyzb[qo + 2],
                                pcx, pcy, pcz));
        if (tid == c) s_cdown = cd;            // this block's refreshed cand
        float v = cd; int i = pi;
        wave_argmax(v, i);
        if (tid == 0) s_lb = v;
    }
    __syncthreads();
    const float LB = s_lb;
    const float cdown = s_cdown;

    // 3. bookkeeping (block 0 only; ws_sel[R-1] has no same-kernel readers)
    if (c == 0 && tid == 0) {
        if constexpr (R == 2) {
            out[b * NPOINT + 0] = 0;
            ws_sel[b * NPOINT + 0] = make_float4(xyzb[0], xyzb[1], xyzb[2], 0.f);
        }
        out[b * NPOINT + (R - 1)] = prevIdx;
        ws_sel[b * NPOINT + (R - 1)] = make_float4(pcx, pcy, pcz, 0.f);
    }

    // 4. prune: stale UB still valid; strict < keeps tie-chunks scannable
    const float ubc = ub_in[b * G + c];
    if (ubc < LB) {
        if (tid == 0) {
            ub_out[b * G + c]   = ubc;
            uidx_out[b * G + c] = uidx_in[b * G + c];
            cand_out[b * G + c] = cdown;
        }
        return;
    }

    // 5. centers 0..R-1 into LDS
    if constexpr (R == 2) {
        if (tid == 0) {
            scx[0] = xyzb[0]; scy[0] = xyzb[1]; scz[0] = xyzb[2];
            scx[1] = pcx;     scy[1] = pcy;     scz[1] = pcz;
        }
    } else {
        if (tid < R - 1) {
            float4 q = ws_sel[b * NPOINT + tid];
            scx[tid] = q.x; scy[tid] = q.y; scz[tid] = q.z;
        }
        if (tid == 0) { scx[R - 1] = pcx; scy[R - 1] = pcy; scz[R - 1] = pcz; }
    }
    __syncthreads();

    // 6. exact rescan + block argmax
    float v; int i;
    scan_chunk<R>(xyzb, c, tid, scx, scy, scz, v, i);
    wave_argmax(v, i);
    if (lane == 0) { s_v[wave] = v; s_i[wave] = i; }
    __syncthreads();
    if (tid == 0) {
        float fv = s_v[0]; int fi = s_i[0];
        #pragma unroll
        for (int w = 1; w < 4; ++w) {
            float ov = s_v[w]; int oi = s_i[w];
            if (ov > fv || (ov == fv && oi < fi)) { fv = ov; fi = oi; }
        }
        ub_out[b * G + c]   = fv;
        uidx_out[b * G + c] = fi;
        cand_out[b * G + c] = fv;
        atomicMax(&win_out[b], packvi(fv, fi));
    }
}

// ---- Final: decode step-9 winners.
__global__ __launch_bounds__(64) void fps_final(
    const unsigned long long* __restrict__ win9, int* __restrict__ out)
{
    const int b = threadIdx.x;
    if (b < NB) out[b * NPOINT + (NPOINT - 1)] = unpack_idx(win9[b]);
}

extern "C" void kernel_launch(void* const* d_in, const int* in_sizes, int n_in,
                              void* d_out, int out_size, void* d_ws, size_t ws_size,
                              hipStream_t stream) {
    const float* xyz = (const float*)d_in[0];
    int* out = (int*)d_out;
    char* ws = (char*)d_ws;

    float*  ub0   = (float*)(ws + 0);        // 16 KB each
    float*  ub1   = (float*)(ws + 16384);
    int*    ux0   = (int*)  (ws + 32768);
    int*    ux1   = (int*)  (ws + 49152);
    float*  cd0   = (float*)(ws + 65536);
    float*  cd1   = (float*)(ws + 81920);
    float4* wsel  = (float4*)(ws + 98304);   // 10 KB
    unsigned long long* win = (unsigned long long*)(ws + 112640); // 10*64*8 = 5120 B

    hipMemsetAsync(win, 0, NPOINT * NB * sizeof(unsigned long long), stream);

    dim3 grid(G, NB), block(TPB);
    fps_scan1<<<grid, block, 0, stream>>>(xyz, ub0, ux0, cd0);

    // step R: parity in/out; win slot R (reads slot R-1)
    fps_step<2><<<grid, block, 0, stream>>>(xyz, out, wsel, ub0, ub1, ux0, ux1, cd0, cd1, win + 1 * NB, win + 2 * NB);
    fps_step<3><<<grid, block, 0, stream>>>(xyz, out, wsel, ub1, ub0, ux1, ux0, cd1, cd0, win + 2 * NB, win + 3 * NB);
    fps_step<4><<<grid, block, 0, stream>>>(xyz, out, wsel, ub0, ub1, ux0, ux1, cd0, cd1, win + 3 * NB, win + 4 * NB);
    fps_step<5><<<grid, block, 0, stream>>>(xyz, out, wsel, ub1, ub0, ux1, ux0, cd1, cd0, win + 4 * NB, win + 5 * NB);
    fps_step<6><<<grid, block, 0, stream>>>(xyz, out, wsel, ub0, ub1, ux0, ux1, cd0, cd1, win + 5 * NB, win + 6 * NB);
    fps_step<7><<<grid, block, 0, stream>>>(xyz, out, wsel, ub1, ub0, ux1, ux0, cd1, cd0, win + 6 * NB, win + 7 * NB);
    fps_step<8><<<grid, block, 0, stream>>>(xyz, out, wsel, ub0, ub1, ux0, ux1, cd0, cd1, win + 7 * NB, win + 8 * NB);
    fps_step<9><<<grid, block, 0, stream>>>(xyz, out, wsel, ub1, ub0, ux1, ux0, cd1, cd0, win + 8 * NB, win + 9 * NB);

    fps_final<<<dim3(1), dim3(64), 0, stream>>>(win + 9 * NB, out);
}